// Round 4
// baseline (104.849 us; speedup 1.0000x reference)
//
#include <hip/hip_runtime.h>
#include <hip/hip_bf16.h>
#include <math.h>

// SimpleMemoryBank: B=8,T=4096,D=512,SLOTS=128,TOPK=8
#define R_TOTAL 32768
#define DM      512
#define NSLOT   128
#define KSEL    8

typedef _Float16 half8 __attribute__((ext_vector_type(8)));
typedef float    floatx4 __attribute__((ext_vector_type(4)));

// ---------------- prep: split K into f16 hi/lo (scaled by 256 so residuals are normal f16) ---
__global__ void smb_splitK(const float* __restrict__ Km,
                           _Float16* __restrict__ K1, _Float16* __restrict__ K2) {
  const int i = blockIdx.x * 256 + threadIdx.x;      // grid covers NSLOT*DM = 65536
  const float f = Km[i] * 256.0f;                    // exact (power of 2)
  const _Float16 h = (_Float16)f;
  K1[i] = h;
  K2[i] = (_Float16)(f - (float)h);                  // f - (float)h exact (Sterbenz)
}

// ---------------- fused main: per-wave 16 rows, no barriers anywhere ------------------------
__global__ __launch_bounds__(256, 2) void smb_main(
    const float* __restrict__ q,     // [R_TOTAL, DM]
    const _Float16* __restrict__ K1, // [NSLOT, DM] hi
    const _Float16* __restrict__ K2, // [NSLOT, DM] lo
    const float* __restrict__ Vm,    // [NSLOT, DM]
    const float* __restrict__ sal,   // [NSLOT]
    float* __restrict__ outv,        // [R_TOTAL, DM]
    float* __restrict__ outw)        // [R_TOTAL, KSEL]
{
  __shared__ float slab[4][16][132];   // per-wave score slab (0 measured bank conflicts)

  const int t  = threadIdx.x;
  const int w  = t >> 6;          // wave 0..3
  const int l  = t & 63;          // lane
  const int li = l & 15;          // M-row / B-col within fragment
  const int kg = l >> 4;          // k-group 0..3
  const int r0w = blockIdx.x * 64 + w * 16;   // this wave's 16 q rows

  const float* qrow = q + (size_t)(r0w + li) * DM + kg * 8;
  const _Float16* k1p = K1 + (size_t)li * DM + kg * 8;
  const _Float16* k2p = K2 + (size_t)li * DM + kg * 8;

  floatx4 acc[8];
#pragma unroll
  for (int g = 0; g < 8; ++g) acc[g] = (floatx4){0.f, 0.f, 0.f, 0.f};

  // ---- Phase A: f16-split MFMA GEMM with explicit chunk double-buffer ----
  // live regs/chunk: B cur+next 2x64, q cur+next 2x8, acc 32, a 8  => ~190, no spill
  float4 q0 = *(const float4*)(qrow + 0);
  float4 q1 = *(const float4*)(qrow + 4);
  half8 b1[8], b2[8];
#pragma unroll
  for (int g = 0; g < 8; ++g) {
    b1[g] = *(const half8*)(k1p + g * 16 * DM);
    b2[g] = *(const half8*)(k2p + g * 16 * DM);
  }

#pragma unroll
  for (int c = 0; c < 16; ++c) {
    float4 q0n, q1n;
    half8 b1n[8], b2n[8];
    if (c < 15) {                       // issue next chunk's loads before computing current
      q0n = *(const float4*)(qrow + (c + 1) * 32);
      q1n = *(const float4*)(qrow + (c + 1) * 32 + 4);
#pragma unroll
      for (int g = 0; g < 8; ++g) {
        b1n[g] = *(const half8*)(k1p + g * 16 * DM + (c + 1) * 32);
        b2n[g] = *(const half8*)(k2p + g * 16 * DM + (c + 1) * 32);
      }
    }
    half8 a1, a2;
#pragma unroll
    for (int j = 0; j < 4; ++j) {
      const float f0 = q0[j] * 16.0f;   // exact scale
      const float f1 = q1[j] * 16.0f;
      const _Float16 h0 = (_Float16)f0;
      const _Float16 h1 = (_Float16)f1;
      a1[j]     = h0;  a2[j]     = (_Float16)(f0 - (float)h0);
      a1[4 + j] = h1;  a2[4 + j] = (_Float16)(f1 - (float)h1);
    }
#pragma unroll
    for (int g = 0; g < 8; ++g) {
      acc[g] = __builtin_amdgcn_mfma_f32_16x16x32_f16(a1, b1[g], acc[g], 0, 0, 0);
      acc[g] = __builtin_amdgcn_mfma_f32_16x16x32_f16(a2, b1[g], acc[g], 0, 0, 0);
      acc[g] = __builtin_amdgcn_mfma_f32_16x16x32_f16(a1, b2[g], acc[g], 0, 0, 0);
    }
    if (c < 15) {
      q0 = q0n; q1 = q1n;
#pragma unroll
      for (int g = 0; g < 8; ++g) { b1[g] = b1n[g]; b2[g] = b2n[g]; }
    }
  }

  // ---- epilogue: scores = (acc/4096)/sqrt(D) + salience; dump to per-wave slab ----
  // D-frag layout (m89-verified): col = lane&15 (slot), row = (lane>>4)*4 + reg (q row)
  const float den = sqrtf((float)DM);
#pragma unroll
  for (int g = 0; g < 8; ++g) {
    const float sv = sal[g * 16 + li];
#pragma unroll
    for (int i = 0; i < 4; ++i) {
      const float s = (acc[g][i] * 0.000244140625f) / den + sv;  // *2^-12 exact, IEEE div
      slab[w][kg * 4 + i][g * 16 + li] = s;
    }
  }
  asm volatile("s_waitcnt lgkmcnt(0)" ::: "memory");   // same-wave LDS write->read fence

  // ---- Phase B: per-row top-8 (tie: lower index) + softmax. 4 lanes/row. ----
  const int row = l >> 2;   // 0..15
  const int lq  = l & 3;

  float bs[8]; int bi[8];
#pragma unroll
  for (int p = 0; p < 8; ++p) { bs[p] = -3.0e38f; bi[p] = 0x7fffffff; }

#pragma unroll
  for (int jj = 0; jj < 32; ++jj) {
    const int   j = jj * 4 + lq;
    const float s = slab[w][row][j];
    bool c[8];
#pragma unroll
    for (int p = 0; p < 8; ++p) c[p] = s > bs[p];   // strict > keeps earlier index on ties
    float nb[8]; int ni[8];
    nb[0] = c[0] ? s : bs[0];
    ni[0] = c[0] ? j : bi[0];
#pragma unroll
    for (int p = 7; p >= 1; --p) {
      nb[p] = c[p] ? (c[p - 1] ? bs[p - 1] : s) : bs[p];
      ni[p] = c[p] ? (c[p - 1] ? bi[p - 1] : j) : bi[p];
    }
#pragma unroll
    for (int p = 0; p < 8; ++p) { bs[p] = nb[p]; bi[p] = ni[p]; }
  }

  // merge 4 sorted lists via quad butterflies (score desc, index asc) + pop
  float ts[8]; int ti_[8];
#pragma unroll
  for (int r = 0; r < 8; ++r) {
    float hs = bs[0]; int hi = bi[0];
    {
      const float os = __shfl_xor(hs, 1, 64);
      const int   oi = __shfl_xor(hi, 1, 64);
      if (os > hs || (os == hs && oi < hi)) { hs = os; hi = oi; }
    }
    {
      const float os = __shfl_xor(hs, 2, 64);
      const int   oi = __shfl_xor(hi, 2, 64);
      if (os > hs || (os == hs && oi < hi)) { hs = os; hi = oi; }
    }
    ts[r] = hs; ti_[r] = hi;
    if (bs[0] == hs && bi[0] == hi) {
#pragma unroll
      for (int p = 0; p < 7; ++p) { bs[p] = bs[p + 1]; bi[p] = bi[p + 1]; }
      bs[7] = -3.0e38f; bi[7] = 0x7fffffff;
    }
  }

  float tw[8];
  const float mx = ts[0];
  float esum = 0.0f;
#pragma unroll
  for (int r = 0; r < 8; ++r) { tw[r] = expf(ts[r] - mx); esum += tw[r]; }
#pragma unroll
  for (int r = 0; r < 8; ++r) tw[r] /= esum;

  if (lq == 0) {
#pragma unroll
    for (int r = 0; r < 8; ++r) outw[(size_t)(r0w + row) * KSEL + r] = tw[r];
  }

  // ---- Phase C: read_vectors = sum_k w_k * V[idx_k]; quad-local (w,i in regs) ----
  const float4* __restrict__ V4 = (const float4*)Vm;
  float4* __restrict__ O4 = (float4*)outv;
  const size_t obase = (size_t)(r0w + row) * (DM / 4);
#pragma unroll 4
  for (int cc = 0; cc < 32; ++cc) {
    const int cdx = cc * 4 + lq;
    float4 a; a.x = a.y = a.z = a.w = 0.0f;
#pragma unroll
    for (int r = 0; r < 8; ++r) {   // k ascending, matches reference einsum order
      const float4 v = V4[(size_t)ti_[r] * (DM / 4) + cdx];
      a.x = fmaf(tw[r], v.x, a.x);
      a.y = fmaf(tw[r], v.y, a.y);
      a.z = fmaf(tw[r], v.z, a.z);
      a.w = fmaf(tw[r], v.w, a.w);
    }
    O4[obase + cdx] = a;
  }
}

extern "C" void kernel_launch(void* const* d_in, const int* in_sizes, int n_in,
                              void* d_out, int out_size, void* d_ws, size_t ws_size,
                              hipStream_t stream) {
  const float* q   = (const float*)d_in[0];
  const float* Km  = (const float*)d_in[1];
  const float* Vm  = (const float*)d_in[2];
  const float* sal = (const float*)d_in[3];
  // d_in[4] = topk (fixed 8)

  float* outv = (float*)d_out;
  float* outw = outv + (size_t)R_TOTAL * DM;

  _Float16* K1 = (_Float16*)d_ws;                 // 128 KB
  _Float16* K2 = K1 + (size_t)NSLOT * DM;         // 128 KB

  hipLaunchKernelGGL(smb_splitK, dim3((NSLOT * DM) / 256), dim3(256), 0, stream, Km, K1, K2);
  hipLaunchKernelGGL(smb_main, dim3(R_TOTAL / 64), dim3(256), 0, stream,
                     q, K1, K2, Vm, sal, outv, outw);
}

// Round 5
// 104.017 us; speedup vs baseline: 1.0080x; 1.0080x over previous
//
#include <hip/hip_runtime.h>
#include <hip/hip_bf16.h>
#include <math.h>

// SimpleMemoryBank: B=8,T=4096,D=512,SLOTS=128,TOPK=8
#define R_TOTAL 32768
#define DM      512
#define NSLOT   128
#define KSEL    8

typedef _Float16 half8 __attribute__((ext_vector_type(8)));
typedef float    floatx4 __attribute__((ext_vector_type(4)));

// ---------------- prep: split K into f16 hi/lo (scaled by 256 so residuals are normal f16) ---
__global__ void smb_splitK(const float* __restrict__ Km,
                           _Float16* __restrict__ K1, _Float16* __restrict__ K2) {
  const int i = blockIdx.x * 256 + threadIdx.x;      // grid covers NSLOT*DM = 65536
  const float f = Km[i] * 256.0f;                    // exact (power of 2)
  const _Float16 h = (_Float16)f;
  K1[i] = h;
  K2[i] = (_Float16)(f - (float)h);                  // f - (float)h exact (Sterbenz)
}

// ---------------- fused main: per-wave 16 rows, no barriers anywhere ------------------------
__global__ __launch_bounds__(256, 2) void smb_main(
    const float* __restrict__ q,     // [R_TOTAL, DM]
    const _Float16* __restrict__ K1, // [NSLOT, DM] hi
    const _Float16* __restrict__ K2, // [NSLOT, DM] lo
    const float* __restrict__ Vm,    // [NSLOT, DM]
    const float* __restrict__ sal,   // [NSLOT]
    float* __restrict__ outv,        // [R_TOTAL, DM]
    float* __restrict__ outw)        // [R_TOTAL, KSEL]
{
  __shared__ float slab[4][16][132];   // per-wave score slab (0 measured bank conflicts)

  const int t  = threadIdx.x;
  const int w  = t >> 6;          // wave 0..3
  const int l  = t & 63;          // lane
  const int li = l & 15;          // M-row / B-col within fragment
  const int kg = l >> 4;          // k-group 0..3
  const int r0w = blockIdx.x * 64 + w * 16;   // this wave's 16 q rows

  const float* qrow = q + (size_t)(r0w + li) * DM + kg * 8;
  const _Float16* k1p = K1 + (size_t)li * DM + kg * 8;
  const _Float16* k2p = K2 + (size_t)li * DM + kg * 8;

  floatx4 acc[8];
#pragma unroll
  for (int g = 0; g < 8; ++g) acc[g] = (floatx4){0.f, 0.f, 0.f, 0.f};

  // ---- Phase A: f16-split MFMA GEMM, software-pipelined.
  // B fragments double-buffered (L2 ~300cyc), q triple-buffered (HBM ~900cyc).
  // sched_barrier(0) per chunk pins load-issue ABOVE compute: without it the
  // scheduler sinks every load to its use (R3/R4: VGPR=68, fully serial chain).
  float4 q0c = *(const float4*)(qrow + 0);
  float4 q1c = *(const float4*)(qrow + 4);
  float4 q0n = *(const float4*)(qrow + 32);
  float4 q1n = *(const float4*)(qrow + 36);
  half8 b1[8], b2[8];
#pragma unroll
  for (int g = 0; g < 8; ++g) {
    b1[g] = *(const half8*)(k1p + g * 16 * DM);
    b2[g] = *(const half8*)(k2p + g * 16 * DM);
  }

#pragma unroll
  for (int c = 0; c < 16; ++c) {
    float4 q0nn, q1nn;
    half8 b1n[8], b2n[8];
    if (c < 14) {                       // q prefetch distance 2
      q0nn = *(const float4*)(qrow + (c + 2) * 32);
      q1nn = *(const float4*)(qrow + (c + 2) * 32 + 4);
    }
    if (c < 15) {                       // B prefetch distance 1
#pragma unroll
      for (int g = 0; g < 8; ++g) {
        b1n[g] = *(const half8*)(k1p + g * 16 * DM + (c + 1) * 32);
        b2n[g] = *(const half8*)(k2p + g * 16 * DM + (c + 1) * 32);
      }
    }
    __builtin_amdgcn_sched_barrier(0);  // loads above, compute below — do not mix

    half8 a1, a2;
#pragma unroll
    for (int j = 0; j < 4; ++j) {
      const float f0 = q0c[j] * 16.0f;  // exact scale
      const float f1 = q1c[j] * 16.0f;
      const _Float16 h0 = (_Float16)f0;
      const _Float16 h1 = (_Float16)f1;
      a1[j]     = h0;  a2[j]     = (_Float16)(f0 - (float)h0);
      a1[4 + j] = h1;  a2[4 + j] = (_Float16)(f1 - (float)h1);
    }
#pragma unroll
    for (int g = 0; g < 8; ++g) {
      acc[g] = __builtin_amdgcn_mfma_f32_16x16x32_f16(a1, b1[g], acc[g], 0, 0, 0);
      acc[g] = __builtin_amdgcn_mfma_f32_16x16x32_f16(a2, b1[g], acc[g], 0, 0, 0);
      acc[g] = __builtin_amdgcn_mfma_f32_16x16x32_f16(a1, b2[g], acc[g], 0, 0, 0);
    }
    // rotate buffers (SSA copies, coalesced by unroll)
    q0c = q0n; q1c = q1n;
    if (c < 14) { q0n = q0nn; q1n = q1nn; }
    if (c < 15) {
#pragma unroll
      for (int g = 0; g < 8; ++g) { b1[g] = b1n[g]; b2[g] = b2n[g]; }
    }
  }

  // ---- epilogue: scores = (acc/4096)/sqrt(D) + salience; dump to per-wave slab ----
  // D-frag layout (m89-verified): col = lane&15 (slot), row = (lane>>4)*4 + reg (q row)
  const float den = sqrtf((float)DM);
#pragma unroll
  for (int g = 0; g < 8; ++g) {
    const float sv = sal[g * 16 + li];
#pragma unroll
    for (int i = 0; i < 4; ++i) {
      const float s = (acc[g][i] * 0.000244140625f) / den + sv;  // *2^-12 exact, IEEE div
      slab[w][kg * 4 + i][g * 16 + li] = s;
    }
  }
  asm volatile("s_waitcnt lgkmcnt(0)" ::: "memory");   // same-wave LDS write->read fence

  // ---- Phase B: per-row top-8 (tie: lower index) + softmax. 4 lanes/row. ----
  const int row = l >> 2;   // 0..15
  const int lq  = l & 3;

  float bs[8]; int bi[8];
#pragma unroll
  for (int p = 0; p < 8; ++p) { bs[p] = -3.0e38f; bi[p] = 0x7fffffff; }

#pragma unroll
  for (int jj = 0; jj < 32; ++jj) {
    const int   j = jj * 4 + lq;
    const float s = slab[w][row][j];
    bool c[8];
#pragma unroll
    for (int p = 0; p < 8; ++p) c[p] = s > bs[p];   // strict > keeps earlier index on ties
    float nb[8]; int ni[8];
    nb[0] = c[0] ? s : bs[0];
    ni[0] = c[0] ? j : bi[0];
#pragma unroll
    for (int p = 7; p >= 1; --p) {
      nb[p] = c[p] ? (c[p - 1] ? bs[p - 1] : s) : bs[p];
      ni[p] = c[p] ? (c[p - 1] ? bi[p - 1] : j) : bi[p];
    }
#pragma unroll
    for (int p = 0; p < 8; ++p) { bs[p] = nb[p]; bi[p] = ni[p]; }
  }

  // merge 4 sorted lists via quad butterflies (score desc, index asc) + pop
  float ts[8]; int ti_[8];
#pragma unroll
  for (int r = 0; r < 8; ++r) {
    float hs = bs[0]; int hi = bi[0];
    {
      const float os = __shfl_xor(hs, 1, 64);
      const int   oi = __shfl_xor(hi, 1, 64);
      if (os > hs || (os == hs && oi < hi)) { hs = os; hi = oi; }
    }
    {
      const float os = __shfl_xor(hs, 2, 64);
      const int   oi = __shfl_xor(hi, 2, 64);
      if (os > hs || (os == hs && oi < hi)) { hs = os; hi = oi; }
    }
    ts[r] = hs; ti_[r] = hi;
    if (bs[0] == hs && bi[0] == hi) {
#pragma unroll
      for (int p = 0; p < 7; ++p) { bs[p] = bs[p + 1]; bi[p] = bi[p + 1]; }
      bs[7] = -3.0e38f; bi[7] = 0x7fffffff;
    }
  }

  float tw[8];
  const float mx = ts[0];
  float esum = 0.0f;
#pragma unroll
  for (int r = 0; r < 8; ++r) { tw[r] = expf(ts[r] - mx); esum += tw[r]; }
#pragma unroll
  for (int r = 0; r < 8; ++r) tw[r] /= esum;

  if (lq == 0) {
#pragma unroll
    for (int r = 0; r < 8; ++r) outw[(size_t)(r0w + row) * KSEL + r] = tw[r];
  }

  // ---- Phase C: read_vectors = sum_k w_k * V[idx_k]; quad-local (w,i in regs) ----
  const float4* __restrict__ V4 = (const float4*)Vm;
  float4* __restrict__ O4 = (float4*)outv;
  const size_t obase = (size_t)(r0w + row) * (DM / 4);
#pragma unroll 4
  for (int cc = 0; cc < 32; ++cc) {
    const int cdx = cc * 4 + lq;
    float4 a; a.x = a.y = a.z = a.w = 0.0f;
#pragma unroll
    for (int r = 0; r < 8; ++r) {   // k ascending, matches reference einsum order
      const float4 v = V4[(size_t)ti_[r] * (DM / 4) + cdx];
      a.x = fmaf(tw[r], v.x, a.x);
      a.y = fmaf(tw[r], v.y, a.y);
      a.z = fmaf(tw[r], v.z, a.z);
      a.w = fmaf(tw[r], v.w, a.w);
    }
    O4[obase + cdx] = a;
  }
}

extern "C" void kernel_launch(void* const* d_in, const int* in_sizes, int n_in,
                              void* d_out, int out_size, void* d_ws, size_t ws_size,
                              hipStream_t stream) {
  const float* q   = (const float*)d_in[0];
  const float* Km  = (const float*)d_in[1];
  const float* Vm  = (const float*)d_in[2];
  const float* sal = (const float*)d_in[3];
  // d_in[4] = topk (fixed 8)

  float* outv = (float*)d_out;
  float* outw = outv + (size_t)R_TOTAL * DM;

  _Float16* K1 = (_Float16*)d_ws;                 // 128 KB
  _Float16* K2 = K1 + (size_t)NSLOT * DM;         // 128 KB

  hipLaunchKernelGGL(smb_splitK, dim3((NSLOT * DM) / 256), dim3(256), 0, stream, Km, K1, K2);
  hipLaunchKernelGGL(smb_main, dim3(R_TOTAL / 64), dim3(256), 0, stream,
                     q, K1, K2, Vm, sal, outv, outw);
}

// Round 6
// 68.963 us; speedup vs baseline: 1.5204x; 1.5083x over previous
//
#include <hip/hip_runtime.h>
#include <hip/hip_bf16.h>
#include <math.h>

// SimpleMemoryBank: B=8,T=4096,D=512,SLOTS=128,TOPK=8
#define R_TOTAL 32768
#define DM      512
#define NSLOT   128
#define KSEL    8

typedef _Float16 half8 __attribute__((ext_vector_type(8)));
typedef float    floatx4 __attribute__((ext_vector_type(4)));

// ---------------- prep: split K into f16 hi/lo (scaled by 256 so residuals are normal f16) ---
__global__ void smb_splitK(const float* __restrict__ Km,
                           _Float16* __restrict__ K1, _Float16* __restrict__ K2) {
  const int i = blockIdx.x * 256 + threadIdx.x;      // grid covers NSLOT*DM = 65536
  const float f = Km[i] * 256.0f;                    // exact (power of 2)
  const _Float16 h = (_Float16)f;
  K1[i] = h;
  K2[i] = (_Float16)(f - (float)h);                  // f - (float)h exact (Sterbenz)
}

// async 16B global->LDS (width literal 16; LDS dest = wave-uniform base + lane*16)
__device__ __forceinline__ void load16_lds(const _Float16* g, _Float16* l) {
  __builtin_amdgcn_global_load_lds(
      (const __attribute__((address_space(1))) unsigned int*)g,
      (__attribute__((address_space(3))) unsigned int*)l, 16, 0, 0);
}

// ---------------- fused main ---------------------------------------------------------------
// Per block: 64 q rows, 4 waves x 16 rows x all 128 slots.
// K chunks staged in LDS (shared by the 4 waves): B regs drop from 128 (R3-R5's
// regalloc-defeating demand -> fully serialized loads) to 32 transient.
__global__ __launch_bounds__(256, 2) void smb_main(
    const float* __restrict__ q,     // [R_TOTAL, DM]
    const _Float16* __restrict__ K1, // [NSLOT, DM] hi
    const _Float16* __restrict__ K2, // [NSLOT, DM] lo
    const float* __restrict__ Vm,    // [NSLOT, DM]
    const float* __restrict__ sal,   // [NSLOT]
    float* __restrict__ outv,        // [R_TOTAL, DM]
    float* __restrict__ outw)        // [R_TOTAL, KSEL]
{
  // stage: plane-major [u = h*4+kg][slot][8 halves]; 16-lane groups read consecutive
  // 16B rows -> 2-way bank alias only (free, m136). 2 x 16 KB double buffer.
  __shared__ _Float16 stage[2][8][NSLOT][8];
  __shared__ float slab[4][16][132];   // per-wave score slab

  const int t  = threadIdx.x;
  const int w  = t >> 6;          // wave 0..3
  const int l  = t & 63;          // lane
  const int li = l & 15;          // M-row / B-col within fragment
  const int kg = l >> 4;          // k-group 0..3
  const int r0w = blockIdx.x * 64 + w * 16;   // this wave's 16 q rows

  const float* qrow = q + (size_t)(r0w + li) * DM + kg * 8;

  // staging assignment: wave w covers planes u = 2w, 2w+1; halves p = 0,1 (4 instrs/wave)
  const int u0 = 2 * w;

  floatx4 acc[8];
#pragma unroll
  for (int g = 0; g < 8; ++g) acc[g] = (floatx4){0.f, 0.f, 0.f, 0.f};

  // ---- prologue: stage chunk 0, load q chunk 0 ----
#pragma unroll
  for (int i = 0; i < 4; ++i) {
    const int u = u0 + (i >> 1);
    const int p = i & 1;
    const _Float16* src = (u < 4 ? K1 : K2) + (size_t)(p * 64 + l) * DM + (u & 3) * 8;
    load16_lds(src, &stage[0][u][p * 64][0]);
  }
  float4 q0c = *(const float4*)(qrow + 0);
  float4 q1c = *(const float4*)(qrow + 4);
  __syncthreads();   // compiler drains vmcnt(0) before s_barrier -> stage(0) resident

  // ---- main loop: stage(c+1) issued BEFORE compute(c); barrier after compute ----
#pragma unroll 2
  for (int c = 0; c < 16; ++c) {
    const int cb = c & 1, nb = cb ^ 1;
    float4 q0n, q1n;
    if (c < 15) {
#pragma unroll
      for (int i = 0; i < 4; ++i) {
        const int u = u0 + (i >> 1);
        const int p = i & 1;
        const _Float16* src = (u < 4 ? K1 : K2)
                            + (size_t)(p * 64 + l) * DM + (c + 1) * 32 + (u & 3) * 8;
        load16_lds(src, &stage[nb][u][p * 64][0]);
      }
      q0n = *(const float4*)(qrow + (c + 1) * 32);
      q1n = *(const float4*)(qrow + (c + 1) * 32 + 4);
    }

    // compute chunk c: fragments from LDS, f16-split MFMA (3 terms)
    half8 a1, a2;
#pragma unroll
    for (int j = 0; j < 4; ++j) {
      const float f0 = q0c[j] * 16.0f;   // exact scale
      const float f1 = q1c[j] * 16.0f;
      const _Float16 h0 = (_Float16)f0;
      const _Float16 h1 = (_Float16)f1;
      a1[j]     = h0;  a2[j]     = (_Float16)(f0 - (float)h0);
      a1[4 + j] = h1;  a2[4 + j] = (_Float16)(f1 - (float)h1);
    }
#pragma unroll
    for (int g = 0; g < 8; ++g) {
      const half8 b1 = *(const half8*)&stage[cb][kg][g * 16 + li][0];
      const half8 b2 = *(const half8*)&stage[cb][4 + kg][g * 16 + li][0];
      acc[g] = __builtin_amdgcn_mfma_f32_16x16x32_f16(a1, b1, acc[g], 0, 0, 0);
      acc[g] = __builtin_amdgcn_mfma_f32_16x16x32_f16(a2, b1, acc[g], 0, 0, 0);
      acc[g] = __builtin_amdgcn_mfma_f32_16x16x32_f16(a1, b2, acc[g], 0, 0, 0);
    }
    q0c = q0n; q1c = q1n;
    __syncthreads();   // all waves done reading stage[cb]; stage(c+1) drained here too
  }

  // ---- epilogue: scores = (acc/4096)/sqrt(D) + salience; dump to per-wave slab ----
  // D-frag layout (m89-verified): col = lane&15 (slot), row = (lane>>4)*4 + reg (q row)
  const float den = sqrtf((float)DM);
#pragma unroll
  for (int g = 0; g < 8; ++g) {
    const float sv = sal[g * 16 + li];
#pragma unroll
    for (int i = 0; i < 4; ++i) {
      const float s = (acc[g][i] * 0.000244140625f) / den + sv;  // *2^-12 exact, IEEE div
      slab[w][kg * 4 + i][g * 16 + li] = s;
    }
  }
  asm volatile("s_waitcnt lgkmcnt(0)" ::: "memory");   // same-wave LDS write->read fence

  // ---- Phase B: per-row top-8 (tie: lower index) + softmax. 4 lanes/row. ----
  const int row = l >> 2;   // 0..15
  const int lq  = l & 3;

  float bs[8]; int bi[8];
#pragma unroll
  for (int p = 0; p < 8; ++p) { bs[p] = -3.0e38f; bi[p] = 0x7fffffff; }

#pragma unroll
  for (int jj = 0; jj < 32; ++jj) {
    const int   j = jj * 4 + lq;
    const float s = slab[w][row][j];
    bool c[8];
#pragma unroll
    for (int p = 0; p < 8; ++p) c[p] = s > bs[p];   // strict > keeps earlier index on ties
    float nb[8]; int ni[8];
    nb[0] = c[0] ? s : bs[0];
    ni[0] = c[0] ? j : bi[0];
#pragma unroll
    for (int p = 7; p >= 1; --p) {
      nb[p] = c[p] ? (c[p - 1] ? bs[p - 1] : s) : bs[p];
      ni[p] = c[p] ? (c[p - 1] ? bi[p - 1] : j) : bi[p];
    }
#pragma unroll
    for (int p = 0; p < 8; ++p) { bs[p] = nb[p]; bi[p] = ni[p]; }
  }

  // merge 4 sorted lists via quad butterflies (score desc, index asc) + pop
  float ts[8]; int ti_[8];
#pragma unroll
  for (int r = 0; r < 8; ++r) {
    float hs = bs[0]; int hi = bi[0];
    {
      const float os = __shfl_xor(hs, 1, 64);
      const int   oi = __shfl_xor(hi, 1, 64);
      if (os > hs || (os == hs && oi < hi)) { hs = os; hi = oi; }
    }
    {
      const float os = __shfl_xor(hs, 2, 64);
      const int   oi = __shfl_xor(hi, 2, 64);
      if (os > hs || (os == hs && oi < hi)) { hs = os; hi = oi; }
    }
    ts[r] = hs; ti_[r] = hi;
    if (bs[0] == hs && bi[0] == hi) {
#pragma unroll
      for (int p = 0; p < 7; ++p) { bs[p] = bs[p + 1]; bi[p] = bi[p + 1]; }
      bs[7] = -3.0e38f; bi[7] = 0x7fffffff;
    }
  }

  float tw[8];
  const float mx = ts[0];
  float esum = 0.0f;
#pragma unroll
  for (int r = 0; r < 8; ++r) { tw[r] = expf(ts[r] - mx); esum += tw[r]; }
#pragma unroll
  for (int r = 0; r < 8; ++r) tw[r] /= esum;

  if (lq == 0) {
#pragma unroll
    for (int r = 0; r < 8; ++r) outw[(size_t)(r0w + row) * KSEL + r] = tw[r];
  }

  // ---- Phase C: read_vectors = sum_k w_k * V[idx_k]; quad-local (w,i in regs) ----
  const float4* __restrict__ V4 = (const float4*)Vm;
  float4* __restrict__ O4 = (float4*)outv;
  const size_t obase = (size_t)(r0w + row) * (DM / 4);
#pragma unroll 4
  for (int cc = 0; cc < 32; ++cc) {
    const int cdx = cc * 4 + lq;
    float4 a; a.x = a.y = a.z = a.w = 0.0f;
#pragma unroll
    for (int r = 0; r < 8; ++r) {   // k ascending, matches reference einsum order
      const float4 v = V4[(size_t)ti_[r] * (DM / 4) + cdx];
      a.x = fmaf(tw[r], v.x, a.x);
      a.y = fmaf(tw[r], v.y, a.y);
      a.z = fmaf(tw[r], v.z, a.z);
      a.w = fmaf(tw[r], v.w, a.w);
    }
    O4[obase + cdx] = a;
  }
}

extern "C" void kernel_launch(void* const* d_in, const int* in_sizes, int n_in,
                              void* d_out, int out_size, void* d_ws, size_t ws_size,
                              hipStream_t stream) {
  const float* q   = (const float*)d_in[0];
  const float* Km  = (const float*)d_in[1];
  const float* Vm  = (const float*)d_in[2];
  const float* sal = (const float*)d_in[3];
  // d_in[4] = topk (fixed 8)

  float* outv = (float*)d_out;
  float* outw = outv + (size_t)R_TOTAL * DM;

  _Float16* K1 = (_Float16*)d_ws;                 // 128 KB
  _Float16* K2 = K1 + (size_t)NSLOT * DM;         // 128 KB

  hipLaunchKernelGGL(smb_splitK, dim3((NSLOT * DM) / 256), dim3(256), 0, stream, Km, K1, K2);
  hipLaunchKernelGGL(smb_main, dim3(R_TOTAL / 64), dim3(256), 0, stream,
                     q, K1, K2, Vm, sal, outv, outw);
}

// Round 7
// 67.668 us; speedup vs baseline: 1.5495x; 1.0191x over previous
//
#include <hip/hip_runtime.h>
#include <hip/hip_bf16.h>
#include <math.h>

// SimpleMemoryBank: B=8,T=4096,D=512,SLOTS=128,TOPK=8
#define R_TOTAL 32768
#define DM      512
#define NSLOT   128
#define KSEL    8

typedef _Float16 half8 __attribute__((ext_vector_type(8)));
typedef float    floatx4 __attribute__((ext_vector_type(4)));

// ---------------- prep: split K into f16 hi/lo (scaled by 256 so residuals are normal f16) ---
__global__ void smb_splitK(const float* __restrict__ Km,
                           _Float16* __restrict__ K1, _Float16* __restrict__ K2) {
  const int i = blockIdx.x * 256 + threadIdx.x;      // grid covers NSLOT*DM = 65536
  const float f = Km[i] * 256.0f;                    // exact (power of 2)
  const _Float16 h = (_Float16)f;
  K1[i] = h;
  K2[i] = (_Float16)(f - (float)h);                  // f - (float)h exact (Sterbenz)
}

// async 16B global->LDS (width literal 16; LDS dest = wave-uniform base + lane*16)
__device__ __forceinline__ void load16_lds(const _Float16* g, _Float16* l) {
  __builtin_amdgcn_global_load_lds(
      (const __attribute__((address_space(1))) unsigned int*)g,
      (__attribute__((address_space(3))) unsigned int*)l, 16, 0, 0);
}

// ---------------- fused main ---------------------------------------------------------------
// 512-thread blocks, 8 waves = 4 row-groups x 2 slot-halves; 64 rows/block, grid 512.
// Occupancy doubles vs R6 (2 -> 4 waves/SIMD): R6 showed ~85% stall at 2 waves/SIMD.
__global__ __launch_bounds__(512, 4) void smb_main(
    const float* __restrict__ q,     // [R_TOTAL, DM]
    const _Float16* __restrict__ K1, // [NSLOT, DM] hi
    const _Float16* __restrict__ K2, // [NSLOT, DM] lo
    const float* __restrict__ Vm,    // [NSLOT, DM]
    const float* __restrict__ sal,   // [NSLOT]
    float* __restrict__ outv,        // [R_TOTAL, DM]
    float* __restrict__ outw)        // [R_TOTAL, KSEL]
{
  // stage: plane-major [u = h*4+kg][slot][8 halves]; contiguous 16B/slot rows ->
  // minimum 2-way bank alias only (free). 2 x 16 KB double buffer, shared by 8 waves.
  __shared__ _Float16 stage[2][8][NSLOT][8];
  __shared__ float slab[64][132];     // block-wide score slab

  const int t  = threadIdx.x;
  const int w  = t >> 6;          // wave 0..7
  const int l  = t & 63;          // lane
  const int li = l & 15;          // M-row / B-col within fragment
  const int kg = l >> 4;          // k-group 0..3
  const int rg = w >> 1;          // row group 0..3
  const int sh = w & 1;           // slot half 0..1
  const int r0b = blockIdx.x * 64;
  const int r0w = r0b + rg * 16;  // this wave's 16 q rows

  const float* qrow = q + (size_t)(r0w + li) * DM + kg * 8;

  floatx4 acc[4];
#pragma unroll
  for (int g = 0; g < 4; ++g) acc[g] = (floatx4){0.f, 0.f, 0.f, 0.f};

  // ---- prologue: stage chunk 0 (wave w -> plane u=w, halves p=0,1), load q chunk 0 ----
#pragma unroll
  for (int p = 0; p < 2; ++p) {
    const _Float16* src = (w < 4 ? K1 : K2) + (size_t)(p * 64 + l) * DM + (w & 3) * 8;
    load16_lds(src, &stage[0][w][p * 64][0]);
  }
  float4 q0c = *(const float4*)(qrow + 0);
  float4 q1c = *(const float4*)(qrow + 4);
  __syncthreads();   // vmcnt(0) drained before s_barrier -> stage(0) resident

  // ---- main loop: stage(c+1) issued BEFORE compute(c); one barrier per chunk ----
#pragma unroll 2
  for (int c = 0; c < 16; ++c) {
    const int cb = c & 1, nb = cb ^ 1;
    float4 q0n, q1n;
    if (c < 15) {
#pragma unroll
      for (int p = 0; p < 2; ++p) {
        const _Float16* src = (w < 4 ? K1 : K2)
                            + (size_t)(p * 64 + l) * DM + (c + 1) * 32 + (w & 3) * 8;
        load16_lds(src, &stage[nb][w][p * 64][0]);
      }
      q0n = *(const float4*)(qrow + (c + 1) * 32);
      q1n = *(const float4*)(qrow + (c + 1) * 32 + 4);
    }

    // compute chunk c: fragments from LDS, f16-split MFMA (3 terms, exact to ~1e-8 rel)
    half8 a1, a2;
#pragma unroll
    for (int j = 0; j < 4; ++j) {
      const float f0 = q0c[j] * 16.0f;   // exact scale
      const float f1 = q1c[j] * 16.0f;
      const _Float16 h0 = (_Float16)f0;
      const _Float16 h1 = (_Float16)f1;
      a1[j]     = h0;  a2[j]     = (_Float16)(f0 - (float)h0);
      a1[4 + j] = h1;  a2[4 + j] = (_Float16)(f1 - (float)h1);
    }
#pragma unroll
    for (int g = 0; g < 4; ++g) {
      const int slot = sh * 64 + g * 16 + li;
      const half8 b1 = *(const half8*)&stage[cb][kg][slot][0];
      const half8 b2 = *(const half8*)&stage[cb][4 + kg][slot][0];
      acc[g] = __builtin_amdgcn_mfma_f32_16x16x32_f16(a1, b1, acc[g], 0, 0, 0);
      acc[g] = __builtin_amdgcn_mfma_f32_16x16x32_f16(a2, b1, acc[g], 0, 0, 0);
      acc[g] = __builtin_amdgcn_mfma_f32_16x16x32_f16(a1, b2, acc[g], 0, 0, 0);
    }
    q0c = q0n; q1c = q1n;
    __syncthreads();   // all waves done reading stage[cb]; stage(c+1) drained here too
  }

  // ---- epilogue: scores = (acc/4096)/sqrt(D) + salience -> block slab ----
  // D-frag layout (m89-verified): col = lane&15 (slot), row = (lane>>4)*4 + reg (q row)
  const float den = sqrtf((float)DM);
#pragma unroll
  for (int g = 0; g < 4; ++g) {
    const int col = sh * 64 + g * 16 + li;
    const float sv = sal[col];
#pragma unroll
    for (int i = 0; i < 4; ++i) {
      const float s = (acc[g][i] * 0.000244140625f) / den + sv;  // *2^-12 exact, IEEE div
      slab[rg * 16 + kg * 4 + i][col] = s;
    }
  }
  __syncthreads();   // slab now written by both slot-half waves

  // ---- Phase B: per-row top-8 (tie: lower index) + softmax. 8 lanes/row. ----
  const int row = t >> 3;   // 0..63
  const int lq  = t & 7;

  float bs[8]; int bi[8];
#pragma unroll
  for (int p = 0; p < 8; ++p) { bs[p] = -3.0e38f; bi[p] = 0x7fffffff; }

#pragma unroll
  for (int jj = 0; jj < 16; ++jj) {
    const int   j = jj * 8 + lq;
    const float s = slab[row][j];
    bool c[8];
#pragma unroll
    for (int p = 0; p < 8; ++p) c[p] = s > bs[p];   // strict > keeps earlier index on ties
    float nb[8]; int ni[8];
    nb[0] = c[0] ? s : bs[0];
    ni[0] = c[0] ? j : bi[0];
#pragma unroll
    for (int p = 7; p >= 1; --p) {
      nb[p] = c[p] ? (c[p - 1] ? bs[p - 1] : s) : bs[p];
      ni[p] = c[p] ? (c[p - 1] ? bi[p - 1] : j) : bi[p];
    }
#pragma unroll
    for (int p = 0; p < 8; ++p) { bs[p] = nb[p]; bi[p] = ni[p]; }
  }

  // merge 8 sorted lists via oct butterflies (score desc, index asc) + pop
  float ts[8]; int ti_[8];
#pragma unroll
  for (int r = 0; r < 8; ++r) {
    float hs = bs[0]; int hi = bi[0];
#pragma unroll
    for (int m = 1; m <= 4; m <<= 1) {
      const float os = __shfl_xor(hs, m, 64);
      const int   oi = __shfl_xor(hi, m, 64);
      if (os > hs || (os == hs && oi < hi)) { hs = os; hi = oi; }
    }
    ts[r] = hs; ti_[r] = hi;
    if (bs[0] == hs && bi[0] == hi) {   // winner lane pops its head (static shift)
#pragma unroll
      for (int p = 0; p < 7; ++p) { bs[p] = bs[p + 1]; bi[p] = bi[p + 1]; }
      bs[7] = -3.0e38f; bi[7] = 0x7fffffff;
    }
  }

  // softmax over the 8 selected scores; all 8 lanes hold the result redundantly
  float tw[8];
  const float mx = ts[0];
  float esum = 0.0f;
#pragma unroll
  for (int r = 0; r < 8; ++r) { tw[r] = expf(ts[r] - mx); esum += tw[r]; }
#pragma unroll
  for (int r = 0; r < 8; ++r) tw[r] /= esum;

  if (lq == 0) {
#pragma unroll
    for (int r = 0; r < 8; ++r) outw[(size_t)(r0b + row) * KSEL + r] = tw[r];
  }

  // ---- Phase C: read_vectors = sum_k w_k * V[idx_k]; top-k state already in registers ----
  const float4* __restrict__ V4 = (const float4*)Vm;
  float4* __restrict__ O4 = (float4*)outv;
  const size_t obase = (size_t)(r0b + row) * (DM / 4);
#pragma unroll 4
  for (int cc = 0; cc < 16; ++cc) {
    const int cdx = cc * 8 + lq;    // 8 lanes cover 128B contiguous per step
    float4 a; a.x = a.y = a.z = a.w = 0.0f;
#pragma unroll
    for (int r = 0; r < 8; ++r) {   // k ascending, matches reference einsum order
      const float4 v = V4[(size_t)ti_[r] * (DM / 4) + cdx];
      a.x = fmaf(tw[r], v.x, a.x);
      a.y = fmaf(tw[r], v.y, a.y);
      a.z = fmaf(tw[r], v.z, a.z);
      a.w = fmaf(tw[r], v.w, a.w);
    }
    O4[obase + cdx] = a;
  }
}

extern "C" void kernel_launch(void* const* d_in, const int* in_sizes, int n_in,
                              void* d_out, int out_size, void* d_ws, size_t ws_size,
                              hipStream_t stream) {
  const float* q   = (const float*)d_in[0];
  const float* Km  = (const float*)d_in[1];
  const float* Vm  = (const float*)d_in[2];
  const float* sal = (const float*)d_in[3];
  // d_in[4] = topk (fixed 8)

  float* outv = (float*)d_out;
  float* outw = outv + (size_t)R_TOTAL * DM;

  _Float16* K1 = (_Float16*)d_ws;                 // 128 KB
  _Float16* K2 = K1 + (size_t)NSLOT * DM;         // 128 KB

  hipLaunchKernelGGL(smb_splitK, dim3((NSLOT * DM) / 256), dim3(256), 0, stream, Km, K1, K2);
  hipLaunchKernelGGL(smb_main, dim3(R_TOTAL / 64), dim3(512), 0, stream,
                     q, K1, K2, Vm, sal, outv, outw);
}

// Round 8
// 56.806 us; speedup vs baseline: 1.8458x; 1.1912x over previous
//
#include <hip/hip_runtime.h>
#include <hip/hip_bf16.h>
#include <math.h>

// SimpleMemoryBank: B=8,T=4096,D=512,SLOTS=128,TOPK=8
#define R_TOTAL 32768
#define DM      512
#define NSLOT   128
#define KSEL    8

typedef _Float16 half8 __attribute__((ext_vector_type(8)));
typedef float    floatx4 __attribute__((ext_vector_type(4)));

// ---------------- prep: split K into f16 hi/lo AND pre-swizzle into chunk-major staged
// layout Ks[c][u][slot][8] (u=0..3 hi-planes kg, u=4..7 lo-planes kg). Each chunk's
// 16 KB is then CONTIGUOUS, so the main kernel's global_load_lds is lane-coalesced
// (R6/R7 staged from row-major K: 64 lanes x stride-1024B = 64-line scatter per instr,
// the time-invariant both rounds shared).
__global__ void smb_prepK(const float* __restrict__ Km, _Float16* __restrict__ Ks) {
  const int i = blockIdx.x * 256 + threadIdx.x;   // 65536 = slot*512 + d
  const int slot = i >> 9;
  const int d    = i & 511;
  const float f  = Km[i] * 256.0f;                // exact (power of 2)
  const _Float16 h  = (_Float16)f;
  const _Float16 lo = (_Float16)(f - (float)h);   // exact residual (Sterbenz)
  const int c  = d >> 5;          // chunk 0..15
  const int kg = (d >> 3) & 3;    // plane-within-chunk 0..3
  const int j  = d & 7;
  Ks[((((c * 8) + kg    ) * NSLOT + slot) << 3) + j] = h;    // hi plane u=kg
  Ks[((((c * 8) + 4 + kg) * NSLOT + slot) << 3) + j] = lo;   // lo plane u=4+kg
}

// async 16B global->LDS (width literal 16; LDS dest = wave-uniform base + lane*16)
__device__ __forceinline__ void load16_lds(const _Float16* g, _Float16* l) {
  __builtin_amdgcn_global_load_lds(
      (const __attribute__((address_space(1))) unsigned int*)g,
      (__attribute__((address_space(3))) unsigned int*)l, 16, 0, 0);
}

// ---------------- fused main ---------------------------------------------------------------
// 512-thread blocks, 8 waves = 4 row-groups x 2 slot-halves; 64 rows/block, grid 512.
__global__ __launch_bounds__(512, 4) void smb_main(
    const float* __restrict__ q,     // [R_TOTAL, DM]
    const _Float16* __restrict__ Ks, // [16][8][NSLOT][8] staged chunk-major split-K
    const float* __restrict__ Vm,    // [NSLOT, DM]
    const float* __restrict__ sal,   // [NSLOT]
    float* __restrict__ outv,        // [R_TOTAL, DM]
    float* __restrict__ outw)        // [R_TOTAL, KSEL]
{
  // stage layout [u][slot][8] identical to R7 (compute side unchanged); source now linear.
  __shared__ _Float16 stage[2][8][NSLOT][8];
  __shared__ float slab[64][132];     // block-wide score slab

  const int t  = threadIdx.x;
  const int w  = t >> 6;          // wave 0..7
  const int l  = t & 63;          // lane
  const int li = l & 15;          // M-row / B-col within fragment
  const int kg = l >> 4;          // k-group 0..3
  const int rg = w >> 1;          // row group 0..3
  const int sh = w & 1;           // slot half 0..1
  const int r0b = blockIdx.x * 64;
  const int r0w = r0b + rg * 16;  // this wave's 16 q rows

  const float* qrow = q + (size_t)(r0w + li) * DM + kg * 8;

  floatx4 acc[4];
#pragma unroll
  for (int g = 0; g < 4; ++g) acc[g] = (floatx4){0.f, 0.f, 0.f, 0.f};

  // ---- prologue: stage chunk 0 (wave w -> plane u=w, 2 coalesced 1KB copies);
  //      q prefetch distance 2 (chunks 0 and 1) ----
#pragma unroll
  for (int p = 0; p < 2; ++p) {
    const _Float16* src = Ks + ((((size_t)0 * 8 + w) * NSLOT + p * 64 + l) << 3);
    load16_lds(src, &stage[0][w][p * 64 + l][0]);
  }
  float4 q0c = *(const float4*)(qrow + 0);
  float4 q1c = *(const float4*)(qrow + 4);
  float4 q0n = *(const float4*)(qrow + 32);
  float4 q1n = *(const float4*)(qrow + 36);
  __syncthreads();   // vmcnt(0) drained before s_barrier -> stage(0) resident

  // ---- main loop: stage(c+1) + q(c+2) issued BEFORE compute(c); one barrier per chunk ----
#pragma unroll 2
  for (int c = 0; c < 16; ++c) {
    const int cb = c & 1, nb = cb ^ 1;
    float4 q0nn, q1nn;
    if (c < 15) {
#pragma unroll
      for (int p = 0; p < 2; ++p) {
        const _Float16* src = Ks + ((((size_t)(c + 1) * 8 + w) * NSLOT + p * 64 + l) << 3);
        load16_lds(src, &stage[nb][w][p * 64 + l][0]);
      }
    }
    if (c < 14) {
      q0nn = *(const float4*)(qrow + (c + 2) * 32);
      q1nn = *(const float4*)(qrow + (c + 2) * 32 + 4);
    }

    // compute chunk c: fragments from LDS, f16-split MFMA (3 terms, ~1e-8 rel exact)
    half8 a1, a2;
#pragma unroll
    for (int j = 0; j < 4; ++j) {
      const float f0 = q0c[j] * 16.0f;   // exact scale
      const float f1 = q1c[j] * 16.0f;
      const _Float16 h0 = (_Float16)f0;
      const _Float16 h1 = (_Float16)f1;
      a1[j]     = h0;  a2[j]     = (_Float16)(f0 - (float)h0);
      a1[4 + j] = h1;  a2[4 + j] = (_Float16)(f1 - (float)h1);
    }
#pragma unroll
    for (int g = 0; g < 4; ++g) {
      const int slot = sh * 64 + g * 16 + li;
      const half8 b1 = *(const half8*)&stage[cb][kg][slot][0];
      const half8 b2 = *(const half8*)&stage[cb][4 + kg][slot][0];
      acc[g] = __builtin_amdgcn_mfma_f32_16x16x32_f16(a1, b1, acc[g], 0, 0, 0);
      acc[g] = __builtin_amdgcn_mfma_f32_16x16x32_f16(a2, b1, acc[g], 0, 0, 0);
      acc[g] = __builtin_amdgcn_mfma_f32_16x16x32_f16(a1, b2, acc[g], 0, 0, 0);
    }
    q0c = q0n; q1c = q1n;
    if (c < 14) { q0n = q0nn; q1n = q1nn; }
    __syncthreads();   // all waves done reading stage[cb]; stage(c+1) drained here too
  }

  // ---- epilogue: scores = (acc/4096)/sqrt(D) + salience -> block slab ----
  // D-frag layout (m89-verified): col = lane&15 (slot), row = (lane>>4)*4 + reg (q row)
  const float den = sqrtf((float)DM);
#pragma unroll
  for (int g = 0; g < 4; ++g) {
    const int col = sh * 64 + g * 16 + li;
    const float sv = sal[col];
#pragma unroll
    for (int i = 0; i < 4; ++i) {
      const float s = (acc[g][i] * 0.000244140625f) / den + sv;  // *2^-12 exact, IEEE div
      slab[rg * 16 + kg * 4 + i][col] = s;
    }
  }
  __syncthreads();   // slab now written by both slot-half waves

  // ---- Phase B: per-row top-8 (tie: lower index) + softmax. 8 lanes/row. ----
  const int row = t >> 3;   // 0..63
  const int lq  = t & 7;

  float bs[8]; int bi[8];
#pragma unroll
  for (int p = 0; p < 8; ++p) { bs[p] = -3.0e38f; bi[p] = 0x7fffffff; }

#pragma unroll
  for (int jj = 0; jj < 16; ++jj) {
    const int   j = jj * 8 + lq;
    const float s = slab[row][j];
    bool c[8];
#pragma unroll
    for (int p = 0; p < 8; ++p) c[p] = s > bs[p];   // strict > keeps earlier index on ties
    float nb[8]; int ni[8];
    nb[0] = c[0] ? s : bs[0];
    ni[0] = c[0] ? j : bi[0];
#pragma unroll
    for (int p = 7; p >= 1; --p) {
      nb[p] = c[p] ? (c[p - 1] ? bs[p - 1] : s) : bs[p];
      ni[p] = c[p] ? (c[p - 1] ? bi[p - 1] : j) : bi[p];
    }
#pragma unroll
    for (int p = 0; p < 8; ++p) { bs[p] = nb[p]; bi[p] = ni[p]; }
  }

  // merge 8 sorted lists via oct butterflies (score desc, index asc) + pop
  float ts[8]; int ti_[8];
#pragma unroll
  for (int r = 0; r < 8; ++r) {
    float hs = bs[0]; int hi = bi[0];
#pragma unroll
    for (int m = 1; m <= 4; m <<= 1) {
      const float os = __shfl_xor(hs, m, 64);
      const int   oi = __shfl_xor(hi, m, 64);
      if (os > hs || (os == hs && oi < hi)) { hs = os; hi = oi; }
    }
    ts[r] = hs; ti_[r] = hi;
    if (bs[0] == hs && bi[0] == hi) {   // winner lane pops its head (static shift)
#pragma unroll
      for (int p = 0; p < 7; ++p) { bs[p] = bs[p + 1]; bi[p] = bi[p + 1]; }
      bs[7] = -3.0e38f; bi[7] = 0x7fffffff;
    }
  }

  // softmax over the 8 selected scores; all 8 lanes hold the result redundantly
  float tw[8];
  const float mx = ts[0];
  float esum = 0.0f;
#pragma unroll
  for (int r = 0; r < 8; ++r) { tw[r] = expf(ts[r] - mx); esum += tw[r]; }
#pragma unroll
  for (int r = 0; r < 8; ++r) tw[r] /= esum;

  if (lq == 0) {
#pragma unroll
    for (int r = 0; r < 8; ++r) outw[(size_t)(r0b + row) * KSEL + r] = tw[r];
  }

  // ---- Phase C: read_vectors = sum_k w_k * V[idx_k]; top-k state already in registers ----
  const float4* __restrict__ V4 = (const float4*)Vm;
  float4* __restrict__ O4 = (float4*)outv;
  const size_t obase = (size_t)(r0b + row) * (DM / 4);
#pragma unroll 4
  for (int cc = 0; cc < 16; ++cc) {
    const int cdx = cc * 8 + lq;    // 8 lanes cover 128B contiguous per step
    float4 a; a.x = a.y = a.z = a.w = 0.0f;
#pragma unroll
    for (int r = 0; r < 8; ++r) {   // k ascending, matches reference einsum order
      const float4 v = V4[(size_t)ti_[r] * (DM / 4) + cdx];
      a.x = fmaf(tw[r], v.x, a.x);
      a.y = fmaf(tw[r], v.y, a.y);
      a.z = fmaf(tw[r], v.z, a.z);
      a.w = fmaf(tw[r], v.w, a.w);
    }
    O4[obase + cdx] = a;
  }
}

extern "C" void kernel_launch(void* const* d_in, const int* in_sizes, int n_in,
                              void* d_out, int out_size, void* d_ws, size_t ws_size,
                              hipStream_t stream) {
  const float* q   = (const float*)d_in[0];
  const float* Km  = (const float*)d_in[1];
  const float* Vm  = (const float*)d_in[2];
  const float* sal = (const float*)d_in[3];
  // d_in[4] = topk (fixed 8)

  float* outv = (float*)d_out;
  float* outw = outv + (size_t)R_TOTAL * DM;

  _Float16* Ks = (_Float16*)d_ws;   // 256 KB staged chunk-major split-K

  hipLaunchKernelGGL(smb_prepK, dim3((NSLOT * DM) / 256), dim3(256), 0, stream, Km, Ks);
  hipLaunchKernelGGL(smb_main, dim3(R_TOTAL / 64), dim3(512), 0, stream,
                     q, Ks, Vm, sal, outv, outw);
}